// Round 1
// baseline (3710.778 us; speedup 1.0000x reference)
//
#include <hip/hip_runtime.h>

#define N_NODES 500000
#define N_EDGES 8000000
#define N_GRAPHS 4096
#define IN_DIM 9
#define HID 64

// v[k] = sum_j w2[k,j]*w3[j]; c = sum_j b2[j]*w3[j]; out[g] = b3
__global__ void gin_precompute(const float* __restrict__ w2,
                               const float* __restrict__ b2,
                               const float* __restrict__ w3,
                               const float* __restrict__ b3,
                               float* __restrict__ out,
                               float* __restrict__ v,
                               float* __restrict__ c) {
    int g = blockIdx.x * blockDim.x + threadIdx.x;
    if (g < N_GRAPHS) out[g] = b3[0];
    if (blockIdx.x == 0) {
        int k = threadIdx.x;
        if (k < HID) {
            float acc = 0.f;
            #pragma unroll
            for (int j = 0; j < HID; ++j) acc += w2[k * HID + j] * w3[j];
            v[k] = acc;
        } else if (k == HID) {
            float acc = 0.f;
            #pragma unroll
            for (int j = 0; j < HID; ++j) acc += b2[j] * w3[j];
            *c = acc;
        }
    }
}

// agg[dst] += x[src] over all edges
__global__ void gin_edge_scatter(const int* __restrict__ ei,
                                 const float* __restrict__ x,
                                 float* __restrict__ agg) {
    int e = blockIdx.x * blockDim.x + threadIdx.x;
    if (e >= N_EDGES) return;
    int src = ei[e];
    int dst = ei[N_EDGES + e];
    const float* xr = x + src * IN_DIM;
    float* ar = agg + dst * IN_DIM;
    #pragma unroll
    for (int k = 0; k < IN_DIM; ++k) {
        atomicAdd(&ar[k], xr[k]);
    }
}

// per node: s = c + sum_j max(b1[j] + sum_k (x+agg)[k]*w1[k,j], 0) * v[j]
// then segmented wave reduction over sorted batch ids -> atomicAdd(out[b], s)
__global__ void gin_node(const float* __restrict__ x,
                         const float* __restrict__ agg,
                         const int* __restrict__ batch,
                         const float* __restrict__ w1,
                         const float* __restrict__ b1,
                         const float* __restrict__ v,
                         const float* __restrict__ c,
                         float* __restrict__ out) {
    __shared__ float w1s[IN_DIM * HID];
    __shared__ float b1s[HID];
    __shared__ float vs[HID];
    __shared__ float cs;
    int t = threadIdx.x;
    for (int idx = t; idx < IN_DIM * HID; idx += blockDim.x) w1s[idx] = w1[idx];
    if (t < HID) { b1s[t] = b1[t]; vs[t] = v[t]; }
    if (t == 0) cs = *c;
    __syncthreads();

    int i = blockIdx.x * blockDim.x + t;
    float s = 0.f;
    int b = -1;
    if (i < N_NODES) {
        float tv[IN_DIM];
        #pragma unroll
        for (int k = 0; k < IN_DIM; ++k)
            tv[k] = x[i * IN_DIM + k] + agg[i * IN_DIM + k];
        s = cs;
        #pragma unroll
        for (int j = 0; j < HID; ++j) {
            float z = b1s[j];
            #pragma unroll
            for (int k = 0; k < IN_DIM; ++k)
                z = fmaf(tv[k], w1s[k * HID + j], z);
            s += fmaxf(z, 0.f) * vs[j];
        }
        b = batch[i];
    }

    // segmented inclusive scan across the 64-lane wave (batch sorted)
    int lane = t & 63;
    #pragma unroll
    for (int off = 1; off < 64; off <<= 1) {
        float so = __shfl_up(s, off);
        int bo = __shfl_up(b, off);
        if (lane >= off && bo == b) s += so;
    }
    int nb = __shfl_down(b, 1);
    bool tail = (lane == 63) || (nb != b);
    if (tail && b >= 0) atomicAdd(&out[b], s);
}

extern "C" void kernel_launch(void* const* d_in, const int* in_sizes, int n_in,
                              void* d_out, int out_size, void* d_ws, size_t ws_size,
                              hipStream_t stream) {
    const float* x     = (const float*)d_in[0];
    const int*   ei    = (const int*)d_in[1];
    const int*   batch = (const int*)d_in[2];
    const float* w1    = (const float*)d_in[3];
    const float* b1    = (const float*)d_in[4];
    const float* w2    = (const float*)d_in[5];
    const float* b2    = (const float*)d_in[6];
    const float* w3    = (const float*)d_in[7];
    const float* b3    = (const float*)d_in[8];
    float* out = (float*)d_out;

    float* agg = (float*)d_ws;                    // N_NODES*IN_DIM floats (18 MB)
    float* v   = agg + (size_t)N_NODES * IN_DIM;  // 64 floats
    float* c   = v + HID;                         // 1 float

    hipMemsetAsync(d_ws, 0, (size_t)N_NODES * IN_DIM * sizeof(float), stream);

    gin_precompute<<<(N_GRAPHS + 255) / 256, 256, 0, stream>>>(w2, b2, w3, b3, out, v, c);

    gin_edge_scatter<<<N_EDGES / 256, 256, 0, stream>>>(ei, x, agg);

    gin_node<<<(N_NODES + 255) / 256, 256, 0, stream>>>(x, agg, batch, w1, b1, v, c, out);
}

// Round 2
// 2014.390 us; speedup vs baseline: 1.8421x; 1.8421x over previous
//
#include <hip/hip_runtime.h>

#define N_NODES 500000
#define N_EDGES 8000000
#define N_GRAPHS 4096
#define IN_DIM 9
#define HID 64
#define TILE 2048
#define NT ((N_NODES + TILE - 1) / TILE)   // 245 blocks
#define BLK 1024

// v[k] = sum_j w2[k,j]*w3[j]; c = sum_j b2[j]*w3[j]; out[g] = b3
__global__ void gin_precompute(const float* __restrict__ w2,
                               const float* __restrict__ b2,
                               const float* __restrict__ w3,
                               const float* __restrict__ b3,
                               float* __restrict__ out,
                               float* __restrict__ v,
                               float* __restrict__ c) {
    int g = blockIdx.x * blockDim.x + threadIdx.x;
    if (g < N_GRAPHS) out[g] = b3[0];
    if (blockIdx.x == 0) {
        int k = threadIdx.x;
        if (k < HID) {
            float acc = 0.f;
            #pragma unroll
            for (int j = 0; j < HID; ++j) acc += w2[k * HID + j] * w3[j];
            v[k] = acc;
        } else if (k == HID) {
            float acc = 0.f;
            #pragma unroll
            for (int j = 0; j < HID; ++j) acc += b2[j] * w3[j];
            *c = acc;
        }
    }
}

// One block owns nodes [blk*TILE, blk*TILE+TILE). Aggregates matching edges
// into an LDS tile (LDS atomics only), then runs the fused MLP + scalar
// collapse and a wave-segmented scan into out[] (few device atomics).
__global__ __launch_bounds__(BLK) void gin_tile(
    const int* __restrict__ ei,        // [2*N_EDGES]: src, then dst
    const float* __restrict__ x,
    const int* __restrict__ batch,
    const float* __restrict__ w1,
    const float* __restrict__ b1,
    const float* __restrict__ v,
    const float* __restrict__ c,
    float* __restrict__ out)
{
    __shared__ float tile[TILE * IN_DIM];    // 72 KB
    __shared__ float w1s[IN_DIM * HID];
    __shared__ float b1s[HID];
    __shared__ float vs[HID];
    __shared__ float cs;

    const int t  = threadIdx.x;
    const int lo = blockIdx.x * TILE;
    const int hi = min(lo + TILE, N_NODES);

    for (int i = t; i < TILE * IN_DIM; i += BLK) tile[i] = 0.f;
    for (int i = t; i < IN_DIM * HID; i += BLK) w1s[i] = w1[i];
    if (t < HID) { b1s[t] = b1[t]; vs[t] = v[t]; }
    if (t == 0) cs = *c;
    __syncthreads();

    // ---- scan all edges, filter dst in [lo, hi), LDS-accumulate x[src] ----
    const int4* dst4 = (const int4*)(ei + N_EDGES);
    const int E4 = N_EDGES / 4;          // 2M, exact
    for (int i = t; i < E4; i += BLK) {
        int4 d = dst4[i];
        int e0 = i * 4;
        #pragma unroll
        for (int k = 0; k < 4; ++k) {
            int dk = (k == 0) ? d.x : (k == 1) ? d.y : (k == 2) ? d.z : d.w;
            if (dk >= lo && dk < hi) {
                int s = ei[e0 + k];
                const float* xr = x + (size_t)s * IN_DIM;
                float* tr = tile + (dk - lo) * IN_DIM;
                #pragma unroll
                for (int q = 0; q < IN_DIM; ++q)
                    atomicAdd(&tr[q], xr[q]);
            }
        }
    }
    __syncthreads();

    // ---- fused MLP + scalar collapse + segmented pooled reduction ----
    for (int n0 = 0; n0 < TILE; n0 += BLK) {
        int n = n0 + t;
        int node = lo + n;
        float s = 0.f;
        int b = -1;
        if (node < hi) {
            float tv[IN_DIM];
            #pragma unroll
            for (int k = 0; k < IN_DIM; ++k)
                tv[k] = x[(size_t)node * IN_DIM + k] + tile[n * IN_DIM + k];
            s = cs;
            #pragma unroll
            for (int j = 0; j < HID; ++j) {
                float z = b1s[j];
                #pragma unroll
                for (int k = 0; k < IN_DIM; ++k)
                    z = fmaf(tv[k], w1s[k * HID + j], z);
                s += fmaxf(z, 0.f) * vs[j];
            }
            b = batch[node];
        }
        // segmented inclusive scan across the 64-lane wave (batch sorted,
        // waves cover consecutive 64-node stripes)
        int lane = t & 63;
        #pragma unroll
        for (int off = 1; off < 64; off <<= 1) {
            float so = __shfl_up(s, off);
            int bo  = __shfl_up(b, off);
            if (lane >= off && bo == b) s += so;
        }
        int nb = __shfl_down(b, 1);
        bool tail = (lane == 63) || (nb != b);
        if (tail && b >= 0) atomicAdd(&out[b], s);
    }
}

extern "C" void kernel_launch(void* const* d_in, const int* in_sizes, int n_in,
                              void* d_out, int out_size, void* d_ws, size_t ws_size,
                              hipStream_t stream) {
    const float* x     = (const float*)d_in[0];
    const int*   ei    = (const int*)d_in[1];
    const int*   batch = (const int*)d_in[2];
    const float* w1    = (const float*)d_in[3];
    const float* b1    = (const float*)d_in[4];
    const float* w2    = (const float*)d_in[5];
    const float* b2    = (const float*)d_in[6];
    const float* w3    = (const float*)d_in[7];
    const float* b3    = (const float*)d_in[8];
    float* out = (float*)d_out;

    float* v = (float*)d_ws;   // 64 floats
    float* c = v + HID;        // 1 float

    gin_precompute<<<(N_GRAPHS + 255) / 256, 256, 0, stream>>>(w2, b2, w3, b3, out, v, c);

    gin_tile<<<NT, BLK, 0, stream>>>(ei, x, batch, w1, b1, v, c, out);
}

// Round 3
// 778.597 us; speedup vs baseline: 4.7660x; 2.5872x over previous
//
#include <hip/hip_runtime.h>

#define N_NODES 500000
#define N_EDGES 8000000
#define N_GRAPHS 4096
#define IN_DIM 9
#define XP 12            // padded row stride (floats) -> 48 B, 16B-aligned
#define HID 64
#define TILE 1024
#define NBINS 512        // >= ceil(N_NODES/TILE) = 489
#define NBINS_USED ((N_NODES + TILE - 1) / TILE)   // 489
#define NSCAT 512        // scatter/hist blocks
#define CHUNK (N_EDGES / NSCAT)                    // 15625 edges per scatter block
#define BLK2 1024

// ---------------- xpad: x[N][9] -> xp[N][12] (cols 9..11 left untouched) ----
__global__ void gin_xpad(const float* __restrict__ x, float* __restrict__ xp) {
    int i = blockIdx.x * blockDim.x + threadIdx.x;
    const int TOT = N_NODES * IN_DIM;
    if (i < TOT) {
        int n = i / IN_DIM, k = i - n * IN_DIM;
        xp[n * XP + k] = x[i];
    }
}

// ---------------- precompute: v = w2@w3, c = b2.w3, out[g] = b3 -------------
__global__ void gin_precompute(const float* __restrict__ w2,
                               const float* __restrict__ b2,
                               const float* __restrict__ w3,
                               const float* __restrict__ b3,
                               float* __restrict__ out,
                               float* __restrict__ v,
                               float* __restrict__ c) {
    int g = blockIdx.x * blockDim.x + threadIdx.x;
    if (g < N_GRAPHS) out[g] = b3[0];
    if (blockIdx.x == 0) {
        int k = threadIdx.x;
        if (k < HID) {
            float acc = 0.f;
            #pragma unroll
            for (int j = 0; j < HID; ++j) acc += w2[k * HID + j] * w3[j];
            v[k] = acc;
        } else if (k == HID) {
            float acc = 0.f;
            #pragma unroll
            for (int j = 0; j < HID; ++j) acc += b2[j] * w3[j];
            *c = acc;
        }
    }
}

// ---------------- hist: cnt[bin*NSCAT + blk] = #edges in blk's chunk w/ dst in bin
__global__ __launch_bounds__(256) void gin_hist(const int* __restrict__ ei,
                                                int* __restrict__ cnt) {
    __shared__ int h[NBINS];
    const int t = threadIdx.x, s = blockIdx.x;
    for (int b = t; b < NBINS; b += 256) h[b] = 0;
    __syncthreads();
    const int* dst = ei + N_EDGES;
    const int e0 = s * CHUNK, e1 = e0 + CHUNK;
    for (int e = e0 + t; e < e1; e += 256)
        atomicAdd(&h[dst[e] >> 10], 1);
    __syncthreads();
    for (int b = t; b < NBINS; b += 256)
        cnt[b * NSCAT + s] = h[b];
}

// ---------------- scan: in-place flat exclusive scan of cnt[NBINS*NSCAT] ----
__global__ __launch_bounds__(1024) void gin_scan(int* __restrict__ cnt) {
    __shared__ int sums[1024];
    const int t = threadIdx.x;
    const int SEG = (NBINS * NSCAT) / 1024;   // 256
    int base = t * SEG;
    int mysum = 0;
    for (int i = 0; i < SEG; ++i) mysum += cnt[base + i];
    sums[t] = mysum;
    __syncthreads();
    // Hillis-Steele inclusive scan over 1024 partials
    for (int off = 1; off < 1024; off <<= 1) {
        int vv = (t >= off) ? sums[t - off] : 0;
        __syncthreads();
        sums[t] += vv;
        __syncthreads();
    }
    int run = sums[t] - mysum;   // exclusive base for this segment
    for (int i = 0; i < SEG; ++i) {
        int tmp = cnt[base + i];
        cnt[base + i] = run;
        run += tmp;
    }
}

// ---------------- scatter: packed[pos] = src | (local<<19), binned by dst ---
__global__ __launch_bounds__(256) void gin_scatter(const int* __restrict__ ei,
                                                   const int* __restrict__ cnt,
                                                   unsigned int* __restrict__ packed) {
    __shared__ int cur[NBINS];
    const int t = threadIdx.x, s = blockIdx.x;
    for (int b = t; b < NBINS; b += 256) cur[b] = cnt[b * NSCAT + s];
    __syncthreads();
    const int* src = ei;
    const int* dst = ei + N_EDGES;
    const int e0 = s * CHUNK, e1 = e0 + CHUNK;
    for (int e = e0 + t; e < e1; e += 256) {
        int d = dst[e];
        int bin = d >> 10;
        int local = d & (TILE - 1);
        int pos = atomicAdd(&cur[bin], 1);
        packed[pos] = (unsigned int)src[e] | ((unsigned int)local << 19);
    }
}

// ---------------- tile: aggregate own bin + fused MLP + pooled scan ---------
__global__ __launch_bounds__(BLK2) void gin_tile_sorted(
    const unsigned int* __restrict__ packed,
    const int* __restrict__ cnt,
    const float* __restrict__ xp,
    const int* __restrict__ batch,
    const float* __restrict__ w1,
    const float* __restrict__ b1,
    const float* __restrict__ v,
    const float* __restrict__ c,
    float* __restrict__ out)
{
    __shared__ float tile[TILE * XP];        // 48 KB
    __shared__ float w1s[IN_DIM * HID];
    __shared__ float b1s[HID];
    __shared__ float vs[HID];
    __shared__ float cs;

    const int t = threadIdx.x;
    const int bin = blockIdx.x;
    const int lo = bin * TILE;

    for (int i = t; i < TILE * XP; i += BLK2) tile[i] = 0.f;
    for (int i = t; i < IN_DIM * HID; i += BLK2) w1s[i] = w1[i];
    if (t < HID) { b1s[t] = b1[t]; vs[t] = v[t]; }
    if (t == 0) cs = *c;
    __syncthreads();

    const int beg = cnt[bin * NSCAT];
    const int end = (bin + 1 < NBINS) ? cnt[(bin + 1) * NSCAT] : N_EDGES;

    for (int p = beg + t; p < end; p += BLK2) {
        unsigned int pk = packed[p];
        int src = (int)(pk & 0x7FFFFu);
        int local = (int)(pk >> 19);
        const float4* xr = (const float4*)(xp + (size_t)src * XP);
        float4 a = xr[0], bq = xr[1], cq = xr[2];
        float* tr = tile + local * XP;
        atomicAdd(&tr[0], a.x); atomicAdd(&tr[1], a.y);
        atomicAdd(&tr[2], a.z); atomicAdd(&tr[3], a.w);
        atomicAdd(&tr[4], bq.x); atomicAdd(&tr[5], bq.y);
        atomicAdd(&tr[6], bq.z); atomicAdd(&tr[7], bq.w);
        atomicAdd(&tr[8], cq.x);
    }
    __syncthreads();

    // fused MLP + scalar collapse + segmented pooled reduction
    int node = lo + t;
    float s = 0.f;
    int b = -1;
    if (node < N_NODES) {
        float tv[IN_DIM];
        #pragma unroll
        for (int k = 0; k < IN_DIM; ++k)
            tv[k] = xp[(size_t)node * XP + k] + tile[t * XP + k];
        s = cs;
        #pragma unroll
        for (int j = 0; j < HID; ++j) {
            float z = b1s[j];
            #pragma unroll
            for (int k = 0; k < IN_DIM; ++k)
                z = fmaf(tv[k], w1s[k * HID + j], z);
            s += fmaxf(z, 0.f) * vs[j];
        }
        b = batch[node];
    }
    int lane = t & 63;
    #pragma unroll
    for (int off = 1; off < 64; off <<= 1) {
        float so = __shfl_up(s, off);
        int bo  = __shfl_up(b, off);
        if (lane >= off && bo == b) s += so;
    }
    int nb = __shfl_down(b, 1);
    bool tail = (lane == 63) || (nb != b);
    if (tail && b >= 0) atomicAdd(&out[b], s);
}

extern "C" void kernel_launch(void* const* d_in, const int* in_sizes, int n_in,
                              void* d_out, int out_size, void* d_ws, size_t ws_size,
                              hipStream_t stream) {
    const float* x     = (const float*)d_in[0];
    const int*   ei    = (const int*)d_in[1];
    const int*   batch = (const int*)d_in[2];
    const float* w1    = (const float*)d_in[3];
    const float* b1    = (const float*)d_in[4];
    const float* w2    = (const float*)d_in[5];
    const float* b2    = (const float*)d_in[6];
    const float* w3    = (const float*)d_in[7];
    const float* b3    = (const float*)d_in[8];
    float* out = (float*)d_out;

    // workspace layout
    float* xp = (float*)d_ws;                                  // 500K*12 floats = 24 MB
    unsigned int* packed = (unsigned int*)(xp + (size_t)N_NODES * XP);  // 8M u32 = 32 MB
    int* cnt = (int*)(packed + N_EDGES);                       // 512*512 ints = 1 MB
    float* v = (float*)(cnt + NBINS * NSCAT);                  // 64 floats
    float* c = v + HID;                                        // 1 float

    gin_xpad<<<(N_NODES * IN_DIM + 255) / 256, 256, 0, stream>>>(x, xp);
    gin_precompute<<<(N_GRAPHS + 255) / 256, 256, 0, stream>>>(w2, b2, w3, b3, out, v, c);
    gin_hist<<<NSCAT, 256, 0, stream>>>(ei, cnt);
    gin_scan<<<1, 1024, 0, stream>>>(cnt);
    gin_scatter<<<NSCAT, 256, 0, stream>>>(ei, cnt, packed);
    gin_tile_sorted<<<NBINS_USED, BLK2, 0, stream>>>(packed, cnt, xp, batch, w1, b1, v, c, out);
}

// Round 4
// 689.852 us; speedup vs baseline: 5.3791x; 1.1286x over previous
//
#include <hip/hip_runtime.h>

#define N_NODES 500000
#define N_EDGES 8000000
#define N_GRAPHS 4096
#define IN_DIM 9
#define XP 12            // padded row stride (floats) -> 48 B, 16B-aligned
#define HID 64
#define TILE 1024
#define NBINS 512        // >= ceil(N_NODES/TILE) = 489
#define NBINS_USED ((N_NODES + TILE - 1) / TILE)   // 489
#define NSCAT 512        // scatter/hist blocks
#define CHUNK (N_EDGES / NSCAT)                    // 15625 edges per scatter block
#define BLK2 1024
#define SCAN_N (NBINS * NSCAT)                     // 262144
#define SCAN_BLOCKS 256                            // 1024 elems per block

// ---------------- xpad: x[N][9] -> xp[N][12] ----
__global__ void gin_xpad(const float* __restrict__ x, float* __restrict__ xp) {
    int i = blockIdx.x * blockDim.x + threadIdx.x;
    const int TOT = N_NODES * IN_DIM;
    if (i < TOT) {
        int n = i / IN_DIM, k = i - n * IN_DIM;
        xp[n * XP + k] = x[i];
    }
}

// ---------------- precompute: v = w2@w3, c = b2.w3, out[g] = b3 -------------
__global__ void gin_precompute(const float* __restrict__ w2,
                               const float* __restrict__ b2,
                               const float* __restrict__ w3,
                               const float* __restrict__ b3,
                               float* __restrict__ out,
                               float* __restrict__ v,
                               float* __restrict__ c) {
    int g = blockIdx.x * blockDim.x + threadIdx.x;
    if (g < N_GRAPHS) out[g] = b3[0];
    if (blockIdx.x == 0) {
        int k = threadIdx.x;
        if (k < HID) {
            float acc = 0.f;
            #pragma unroll
            for (int j = 0; j < HID; ++j) acc += w2[k * HID + j] * w3[j];
            v[k] = acc;
        } else if (k == HID) {
            float acc = 0.f;
            #pragma unroll
            for (int j = 0; j < HID; ++j) acc += b2[j] * w3[j];
            *c = acc;
        }
    }
}

// ---------------- hist: cnt[bin*NSCAT + blk] = #edges in blk's chunk w/ dst in bin
__global__ __launch_bounds__(256) void gin_hist(const int* __restrict__ ei,
                                                int* __restrict__ cnt) {
    __shared__ int h[NBINS];
    const int t = threadIdx.x, s = blockIdx.x;
    for (int b = t; b < NBINS; b += 256) h[b] = 0;
    __syncthreads();
    const int* dst = ei + N_EDGES;
    const int e0 = s * CHUNK, e1 = e0 + CHUNK;
    for (int e = e0 + t; e < e1; e += 256)
        atomicAdd(&h[dst[e] >> 10], 1);
    __syncthreads();
    for (int b = t; b < NBINS; b += 256)
        cnt[b * NSCAT + s] = h[b];
}

// ---------------- parallel exclusive scan of cnt[SCAN_N] --------------------
// A: per-block (1024 elems) exclusive scan in place + block sums -> aux
__global__ __launch_bounds__(256) void gin_scan_a(int* __restrict__ cnt,
                                                  int* __restrict__ aux) {
    __shared__ int wtot[4];
    const int t = threadIdx.x, blk = blockIdx.x;
    int4* p = (int4*)(cnt + blk * 1024);
    int4 vv = p[t];
    int s0 = vv.x, s1 = s0 + vv.y, s2 = s1 + vv.z, s3 = s2 + vv.w;
    int lane = t & 63, w = t >> 6;
    int ws = s3;
    #pragma unroll
    for (int off = 1; off < 64; off <<= 1) {
        int o = __shfl_up(ws, off);
        if (lane >= off) ws += o;
    }
    if (lane == 63) wtot[w] = ws;
    __syncthreads();
    int wbase = 0;
    for (int i = 0; i < w; ++i) wbase += wtot[i];
    int excl = wbase + (ws - s3);
    int4 o4;
    o4.x = excl; o4.y = excl + s0; o4.z = excl + s1; o4.w = excl + s2;
    p[t] = o4;
    if (t == 255) aux[blk] = wbase + ws;   // block total
}

// B: exclusive scan of aux[256] (one wave, 4 elems/thread)
__global__ __launch_bounds__(64) void gin_scan_b(int* __restrict__ aux) {
    const int t = threadIdx.x;
    int4* p = (int4*)aux;
    int4 vv = p[t];
    int s0 = vv.x, s1 = s0 + vv.y, s2 = s1 + vv.z, s3 = s2 + vv.w;
    int ws = s3;
    #pragma unroll
    for (int off = 1; off < 64; off <<= 1) {
        int o = __shfl_up(ws, off);
        if (t >= off) ws += o;
    }
    int excl = ws - s3;
    int4 o4;
    o4.x = excl; o4.y = excl + s0; o4.z = excl + s1; o4.w = excl + s2;
    p[t] = o4;
}

// C: add block base
__global__ __launch_bounds__(256) void gin_scan_c(int* __restrict__ cnt,
                                                  const int* __restrict__ aux) {
    const int t = threadIdx.x, blk = blockIdx.x;
    int base = aux[blk];
    int4* p = (int4*)(cnt + blk * 1024);
    int4 vv = p[t];
    vv.x += base; vv.y += base; vv.z += base; vv.w += base;
    p[t] = vv;
}

// ---------------- scatter: packed[pos] = src | (local<<19), binned by dst ---
__global__ __launch_bounds__(256) void gin_scatter(const int* __restrict__ ei,
                                                   const int* __restrict__ cnt,
                                                   unsigned int* __restrict__ packed) {
    __shared__ int cur[NBINS];
    const int t = threadIdx.x, s = blockIdx.x;
    for (int b = t; b < NBINS; b += 256) cur[b] = cnt[b * NSCAT + s];
    __syncthreads();
    const int* src = ei;
    const int* dst = ei + N_EDGES;
    const int e0 = s * CHUNK, e1 = e0 + CHUNK;
    for (int e = e0 + t; e < e1; e += 256) {
        int d = dst[e];
        int bin = d >> 10;
        int local = d & (TILE - 1);
        int pos = atomicAdd(&cur[bin], 1);
        packed[pos] = (unsigned int)src[e] | ((unsigned int)local << 19);
    }
}

// ---------------- tile: aggregate own bin + fused MLP + pooled scan ---------
__global__ __launch_bounds__(BLK2) void gin_tile_sorted(
    const unsigned int* __restrict__ packed,
    const int* __restrict__ cnt,
    const float* __restrict__ xp,
    const int* __restrict__ batch,
    const float* __restrict__ w1,
    const float* __restrict__ b1,
    const float* __restrict__ v,
    const float* __restrict__ c,
    float* __restrict__ out)
{
    __shared__ float tile[TILE * XP];        // 48 KB
    __shared__ float w1s[IN_DIM * HID];
    __shared__ float b1s[HID];
    __shared__ float vs[HID];
    __shared__ float cs;

    const int t = threadIdx.x;
    const int bin = blockIdx.x;
    const int lo = bin * TILE;

    for (int i = t; i < TILE * XP; i += BLK2) tile[i] = 0.f;
    for (int i = t; i < IN_DIM * HID; i += BLK2) w1s[i] = w1[i];
    if (t < HID) { b1s[t] = b1[t]; vs[t] = v[t]; }
    if (t == 0) cs = *c;
    __syncthreads();

    const int beg = cnt[bin * NSCAT];
    const int end = (bin + 1 < NBINS) ? cnt[(bin + 1) * NSCAT] : N_EDGES;

    int p = beg + t;
    // 4x-unrolled gather: batch the loads to raise memory-level parallelism
    for (; p + 3 * BLK2 < end; p += 4 * BLK2) {
        unsigned int pk0 = packed[p];
        unsigned int pk1 = packed[p + BLK2];
        unsigned int pk2 = packed[p + 2 * BLK2];
        unsigned int pk3 = packed[p + 3 * BLK2];
        const float4* x0 = (const float4*)(xp + (size_t)(pk0 & 0x7FFFFu) * XP);
        const float4* x1 = (const float4*)(xp + (size_t)(pk1 & 0x7FFFFu) * XP);
        const float4* x2 = (const float4*)(xp + (size_t)(pk2 & 0x7FFFFu) * XP);
        const float4* x3 = (const float4*)(xp + (size_t)(pk3 & 0x7FFFFu) * XP);
        float4 a0 = x0[0], b0 = x0[1], c0 = x0[2];
        float4 a1 = x1[0], b1_ = x1[1], c1 = x1[2];
        float4 a2 = x2[0], b2_ = x2[1], c2 = x2[2];
        float4 a3 = x3[0], b3_ = x3[1], c3 = x3[2];
        float* t0 = tile + (pk0 >> 19) * XP;
        float* t1 = tile + (pk1 >> 19) * XP;
        float* t2 = tile + (pk2 >> 19) * XP;
        float* t3 = tile + (pk3 >> 19) * XP;
        atomicAdd(&t0[0], a0.x); atomicAdd(&t0[1], a0.y); atomicAdd(&t0[2], a0.z);
        atomicAdd(&t0[3], a0.w); atomicAdd(&t0[4], b0.x); atomicAdd(&t0[5], b0.y);
        atomicAdd(&t0[6], b0.z); atomicAdd(&t0[7], b0.w); atomicAdd(&t0[8], c0.x);
        atomicAdd(&t1[0], a1.x); atomicAdd(&t1[1], a1.y); atomicAdd(&t1[2], a1.z);
        atomicAdd(&t1[3], a1.w); atomicAdd(&t1[4], b1_.x); atomicAdd(&t1[5], b1_.y);
        atomicAdd(&t1[6], b1_.z); atomicAdd(&t1[7], b1_.w); atomicAdd(&t1[8], c1.x);
        atomicAdd(&t2[0], a2.x); atomicAdd(&t2[1], a2.y); atomicAdd(&t2[2], a2.z);
        atomicAdd(&t2[3], a2.w); atomicAdd(&t2[4], b2_.x); atomicAdd(&t2[5], b2_.y);
        atomicAdd(&t2[6], b2_.z); atomicAdd(&t2[7], b2_.w); atomicAdd(&t2[8], c2.x);
        atomicAdd(&t3[0], a3.x); atomicAdd(&t3[1], a3.y); atomicAdd(&t3[2], a3.z);
        atomicAdd(&t3[3], a3.w); atomicAdd(&t3[4], b3_.x); atomicAdd(&t3[5], b3_.y);
        atomicAdd(&t3[6], b3_.z); atomicAdd(&t3[7], b3_.w); atomicAdd(&t3[8], c3.x);
    }
    for (; p < end; p += BLK2) {
        unsigned int pk = packed[p];
        const float4* xr = (const float4*)(xp + (size_t)(pk & 0x7FFFFu) * XP);
        float4 a = xr[0], bq = xr[1], cq = xr[2];
        float* tr = tile + (pk >> 19) * XP;
        atomicAdd(&tr[0], a.x); atomicAdd(&tr[1], a.y); atomicAdd(&tr[2], a.z);
        atomicAdd(&tr[3], a.w); atomicAdd(&tr[4], bq.x); atomicAdd(&tr[5], bq.y);
        atomicAdd(&tr[6], bq.z); atomicAdd(&tr[7], bq.w); atomicAdd(&tr[8], cq.x);
    }
    __syncthreads();

    // fused MLP + scalar collapse + segmented pooled reduction
    int node = lo + t;
    float s = 0.f;
    int b = -1;
    if (node < N_NODES) {
        float tv[IN_DIM];
        #pragma unroll
        for (int k = 0; k < IN_DIM; ++k)
            tv[k] = xp[(size_t)node * XP + k] + tile[t * XP + k];
        s = cs;
        #pragma unroll
        for (int j = 0; j < HID; ++j) {
            float z = b1s[j];
            #pragma unroll
            for (int k = 0; k < IN_DIM; ++k)
                z = fmaf(tv[k], w1s[k * HID + j], z);
            s += fmaxf(z, 0.f) * vs[j];
        }
        b = batch[node];
    }
    int lane = t & 63;
    #pragma unroll
    for (int off = 1; off < 64; off <<= 1) {
        float so = __shfl_up(s, off);
        int bo  = __shfl_up(b, off);
        if (lane >= off && bo == b) s += so;
    }
    int nb = __shfl_down(b, 1);
    bool tail = (lane == 63) || (nb != b);
    if (tail && b >= 0) atomicAdd(&out[b], s);
}

extern "C" void kernel_launch(void* const* d_in, const int* in_sizes, int n_in,
                              void* d_out, int out_size, void* d_ws, size_t ws_size,
                              hipStream_t stream) {
    const float* x     = (const float*)d_in[0];
    const int*   ei    = (const int*)d_in[1];
    const int*   batch = (const int*)d_in[2];
    const float* w1    = (const float*)d_in[3];
    const float* b1    = (const float*)d_in[4];
    const float* w2    = (const float*)d_in[5];
    const float* b2    = (const float*)d_in[6];
    const float* w3    = (const float*)d_in[7];
    const float* b3    = (const float*)d_in[8];
    float* out = (float*)d_out;

    // workspace layout
    float* xp = (float*)d_ws;                                  // 24 MB
    unsigned int* packed = (unsigned int*)(xp + (size_t)N_NODES * XP);  // 32 MB
    int* cnt = (int*)(packed + N_EDGES);                       // 1 MB
    int* aux = cnt + SCAN_N;                                   // 256 ints
    float* v = (float*)(aux + SCAN_BLOCKS);                    // 64 floats
    float* c = v + HID;                                        // 1 float

    gin_xpad<<<(N_NODES * IN_DIM + 255) / 256, 256, 0, stream>>>(x, xp);
    gin_precompute<<<(N_GRAPHS + 255) / 256, 256, 0, stream>>>(w2, b2, w3, b3, out, v, c);
    gin_hist<<<NSCAT, 256, 0, stream>>>(ei, cnt);
    gin_scan_a<<<SCAN_BLOCKS, 256, 0, stream>>>(cnt, aux);
    gin_scan_b<<<1, 64, 0, stream>>>(aux);
    gin_scan_c<<<SCAN_BLOCKS, 256, 0, stream>>>(cnt, aux);
    gin_scatter<<<NSCAT, 256, 0, stream>>>(ei, cnt, packed);
    gin_tile_sorted<<<NBINS_USED, BLK2, 0, stream>>>(packed, cnt, xp, batch, w1, b1, v, c, out);
}